// Round 13
// baseline (391.998 us; speedup 1.0000x reference)
//
#include <hip/hip_runtime.h>
#include <cstdint>
#include <cstddef>

#define B_ 16
#define NROW 1024      // E == N == 1024
#define H_ 128
#define NW 16          // u64 words per 1024-bit adjacency row
#define NEXT 144       // padded V columns: 128 data + ones(128) + 15 zero

typedef unsigned short u16;
typedef unsigned long long u64;
typedef __attribute__((ext_vector_type(8))) short short8;   // 8 bf16 (4 VGPRs)
typedef __attribute__((ext_vector_type(4))) float f32x4;    // MFMA C/D

__device__ __forceinline__ u16 f2bf(float f) {   // RTNE float->bf16
    unsigned u = __float_as_uint(f);
    return (u16)((u + 0x7fffu + ((u >> 16) & 1u)) >> 16);
}

// --- adj (B,E,N) f32 -> bit matrix (B*E rows x 16 u64 words) ---
__global__ void adj_to_bits(const float* __restrict__ adj, u64* __restrict__ bits) {
    int be = blockIdx.x;                      // 16384
    const float* row = adj + (size_t)be * NROW;
    int tid = threadIdx.x, lane = tid & 63, wv = tid >> 6;
    for (int c0 = 0; c0 < NROW; c0 += 256) {
        float v = row[c0 + tid];
        u64 m = __ballot(v != 0.0f);
        if (lane == 0) bits[(size_t)be * NW + (c0 >> 6) + wv] = m;
    }
}

// --- bits -> {0,1} bf16 matrix (edge_init's A operand; lands in W buffer) ---
__global__ void bits_to_abf(const u64* __restrict__ bits, u16* __restrict__ abf) {
    int idx = blockIdx.x * 256 + threadIdx.x;   // word index, 262144 total
    u64 m = bits[idx];
    ushort4* dst = (ushort4*)(abf + (size_t)idx * 64);
#pragma unroll
    for (int j = 0; j < 16; ++j) {
        ushort4 v;
        v.x = ((m >> (j * 4 + 0)) & 1) ? 0x3F80 : 0;
        v.y = ((m >> (j * 4 + 1)) & 1) ? 0x3F80 : 0;
        v.z = ((m >> (j * 4 + 2)) & 1) ? 0x3F80 : 0;
        v.w = ((m >> (j * 4 + 3)) & 1) ? 0x3F80 : 0;
        dst[j] = v;
    }
}

// --- fp32 -> bf16 copy (nodes row-major), 4 elems/thread ---
__global__ void to_bf16(const float* __restrict__ in, u16* __restrict__ out) {
    int i = blockIdx.x * 256 + threadIdx.x;
    float4 v = ((const float4*)in)[i];
    ushort4 r;
    r.x = f2bf(v.x); r.y = f2bf(v.y); r.z = f2bf(v.z); r.w = f2bf(v.w);
    ((ushort4*)out)[i] = r;
}

// --- VT_nodes: vt[b][d][n] = bf16(nodes[b][n][d]); d==128 -> 1; d>128 -> 0 ---
__global__ void trans_vtn(const float* __restrict__ src, u16* __restrict__ vt) {
    int blk = blockIdx.x;                 // B_*NEXT = 2304
    int b = blk / NEXT, d = blk - b * NEXT;
    int t = threadIdx.x;                  // 256 threads x 4 n each
    ushort4 o;
    if (d < H_) {
        const float* sp = src + ((size_t)b << 10) * H_ + d;
        o.x = f2bf(sp[(size_t)(t * 4 + 0) * H_]);
        o.y = f2bf(sp[(size_t)(t * 4 + 1) * H_]);
        o.z = f2bf(sp[(size_t)(t * 4 + 2) * H_]);
        o.w = f2bf(sp[(size_t)(t * 4 + 3) * H_]);
    } else {
        u16 c = (d == H_) ? 0x3F80 : 0;
        o.x = c; o.y = c; o.z = c; o.w = c;
    }
    ((ushort4*)(vt + ((size_t)b * NEXT + d) * NROW))[t] = o;
}

// --- fill constant rows 128..143 of a VT array (ones row + zeros) ---
__global__ void fill_vt_rows(u16* __restrict__ vt) {
    int idx = blockIdx.x * 256 + threadIdx.x;   // 65536: b|r|c
    int b = idx >> 12, r = (idx >> 8) & 15, c = idx & 255;
    u16 v = (r == 0) ? 0x3F80 : 0;
    ushort4 q; q.x = v; q.y = v; q.z = v; q.w = v;
    ((ushort4*)(vt + ((size_t)b * NEXT + H_ + r) * NROW))[c] = q;
}

// --- qs[b][r][k] = bf16(src[b][r][k] * w[k] * log2e) ---
__global__ void prep_q(const float* __restrict__ src, const float* __restrict__ w,
                       u16* __restrict__ qs) {
    int idx = blockIdx.x * 256 + threadIdx.x;   // float4 index, 524288 total
    float4 v = ((const float4*)src)[idx];
    float4 wv = ((const float4*)w)[idx & 31];
    const float L2E = 1.44269504f;
    ushort4 r;
    r.x = f2bf(v.x * wv.x * L2E);
    r.y = f2bf(v.y * wv.y * L2E);
    r.z = f2bf(v.z * wv.z * L2E);
    r.w = f2bf(v.w * wv.w * L2E);
    ((ushort4*)qs)[idx] = r;
}

// --- GEMM1: W[row][col] = mask ? exp2(leaky(qs[row]·kv[col] + wb)) : 0 ---
// 128x128 tile, K=128 single stage. A = qs [m][k], B = kv_bf [n][k] (NT gemm).
// XOR-swizzled LDS (uint4 index ^ (row&7)) on write AND read -> conflict-free.
// TM=0 (alpha): mask bit = bits[e=row][n=col]. TM=1 (beta): bit = bits[e=col][n=row].
__global__ void __launch_bounds__(256, 2)
gemm_score(const u16* __restrict__ qs, const u16* __restrict__ kvbf,
           const u64* __restrict__ bits, const float* __restrict__ w,
           u16* __restrict__ Wout, int TM) {
    __shared__ uint4 Al[2048];   // 128 rows x 16 chunks (32 KB)
    __shared__ uint4 Bl[2048];   // 32 KB
    int blk = blockIdx.x;
    int b = blk >> 6, tt = blk & 63, mt = tt >> 3, nt = tt & 7;
    int t = threadIdx.x;
    const uint4* Ag = (const uint4*)qs + ((size_t)(b << 10) + mt * 128) * 16;
    const uint4* Bg = (const uint4*)kvbf + ((size_t)(b << 10) + nt * 128) * 16;
#pragma unroll
    for (int i = 0; i < 8; ++i) {
        int gi = i * 256 + t;
        int row = gi >> 4, kc = gi & 15;
        Al[row * 16 + (kc ^ (row & 7))] = Ag[gi];
    }
#pragma unroll
    for (int i = 0; i < 8; ++i) {
        int gi = i * 256 + t;
        int row = gi >> 4, kc = gi & 15;
        Bl[row * 16 + (kc ^ (row & 7))] = Bg[gi];
    }
    __syncthreads();
    int lane = t & 63, wv = t >> 6;
    int mw = wv >> 1, nw = wv & 1;
    int r15 = lane & 15, g = lane >> 4;
    f32x4 acc[4][4] = {};
#pragma unroll
    for (int kk = 0; kk < 4; ++kk) {
        short8 a[4], bb[4];
#pragma unroll
        for (int mi = 0; mi < 4; ++mi) {
            int row = mw * 64 + mi * 16 + r15;
            uint4 v = Al[row * 16 + ((kk * 4 + g) ^ (r15 & 7))];
            a[mi] = __builtin_bit_cast(short8, v);
        }
#pragma unroll
        for (int ni = 0; ni < 4; ++ni) {
            int row = nw * 64 + ni * 16 + r15;
            uint4 v = Bl[row * 16 + ((kk * 4 + g) ^ (r15 & 7))];
            bb[ni] = __builtin_bit_cast(short8, v);
        }
#pragma unroll
        for (int mi = 0; mi < 4; ++mi)
#pragma unroll
            for (int ni = 0; ni < 4; ++ni)
                acc[mi][ni] = __builtin_amdgcn_mfma_f32_16x16x32_bf16(
                    a[mi], bb[ni], acc[mi][ni], 0, 0, 0);
    }
    float wb = w[H_] * 1.44269504f;
#pragma unroll
    for (int mi = 0; mi < 4; ++mi) {
#pragma unroll
        for (int reg = 0; reg < 4; ++reg) {
            int row_l = mw * 64 + mi * 16 + g * 4 + reg;   // C/D: row=(lane>>4)*4+reg
#pragma unroll
            for (int ni = 0; ni < 4; ++ni) {
                int col_l = nw * 64 + ni * 16 + r15;       // C/D: col=lane&15
                float p = acc[mi][ni][reg] + wb;
                p = p >= 0.f ? p : 0.2f * p;               // LeakyReLU(0.2)
                int er   = TM ? (nt * 128 + col_l) : (mt * 128 + row_l);
                int bcol = TM ? row_l : col_l;
                u64 wrd = bits[((size_t)(b << 10) + er) * NW + (TM ? mt : nt) * 2 + (bcol >> 6)];
                float ww = ((wrd >> (bcol & 63)) & 1) ? exp2f(p) : 0.f;
                Wout[((size_t)(b << 10) + mt * 128 + row_l) * 1024 + nt * 128 + col_l] = f2bf(ww);
            }
        }
    }
}

// --- GEMM2: out[m][d] = (W[m][:]·Vext[:][d]) / (W[m][:]·ones), d<128 ---
// A = W [m][k=1024] bf16; B = VT [d][k] (pre-transposed, NEXT=144 rows,
// row 128 = ones -> denominator lands in acc[8] col 128). M-tile 64, BK 64.
// aux=1 additionally writes bf16 row-major copy + VT-layout copy of output.
// Also serves edge_init (A = adj-as-bf16; ones-col = degree).
__global__ void __launch_bounds__(256, 2)
gemm_av(const u16* __restrict__ Wsrc, const u16* __restrict__ vt,
        float* __restrict__ outf, u16* __restrict__ bfo, u16* __restrict__ vto,
        int aux) {
    __shared__ uint4 Al[512];     // 64 x 8 (8 KB)
    __shared__ uint4 Bl[1152];    // 144 x 8 (18 KB)
    int blk = blockIdx.x;         // 256
    int b = blk >> 4, mt = blk & 15;
    int t = threadIdx.x;
    int lane = t & 63, wv = t >> 6;
    int r15 = lane & 15, g = lane >> 4;
    f32x4 acc[9] = {};
    const uint4* Agb = (const uint4*)Wsrc + ((size_t)(b << 10) + mt * 64) * 128;
    const uint4* Bgb = (const uint4*)vt + (size_t)b * NEXT * 128;
    for (int kt = 0; kt < 16; ++kt) {
#pragma unroll
        for (int i = 0; i < 2; ++i) {
            int gi = i * 256 + t;            // 0..511
            int row = gi >> 3, kc = gi & 7;
            Al[row * 8 + (kc ^ (row & 7))] = Agb[(size_t)row * 128 + kt * 8 + kc];
        }
#pragma unroll
        for (int i = 0; i < 5; ++i) {
            int gi = i * 256 + t;
            if (gi < 1152) {
                int row = gi >> 3, kc = gi & 7;
                Bl[row * 8 + (kc ^ (row & 7))] = Bgb[(size_t)row * 128 + kt * 8 + kc];
            }
        }
        __syncthreads();
#pragma unroll
        for (int kk = 0; kk < 2; ++kk) {
            int arow = wv * 16 + r15;
            uint4 av = Al[arow * 8 + ((kk * 4 + g) ^ (r15 & 7))];
            short8 a = __builtin_bit_cast(short8, av);
#pragma unroll
            for (int ni = 0; ni < 9; ++ni) {
                int brow = ni * 16 + r15;
                uint4 bv = Bl[brow * 8 + ((kk * 4 + g) ^ (r15 & 7))];
                short8 bb = __builtin_bit_cast(short8, bv);
                acc[ni] = __builtin_amdgcn_mfma_f32_16x16x32_bf16(a, bb, acc[ni], 0, 0, 0);
            }
        }
        __syncthreads();
    }
    int m0 = mt * 64 + wv * 16 + g * 4;
#pragma unroll
    for (int reg = 0; reg < 4; ++reg) {
        float den = __shfl(acc[8][reg], (g << 4));   // col 128 (ones) lives at r15==0
        float rden = den > 0.f ? 1.0f / den : 0.f;
        int mm = m0 + reg;
        size_t obase = (((size_t)(b << 10)) + mm) * H_;
#pragma unroll
        for (int ni = 0; ni < 8; ++ni) {
            int d = ni * 16 + r15;
            float val = acc[ni][reg] * rden;
            outf[obase + d] = val;
            if (aux) {
                u16 hv = f2bf(val);
                bfo[obase + d] = hv;
                vto[((size_t)b * NEXT + d) * NROW + mm] = hv;
            }
        }
    }
}

extern "C" void kernel_launch(void* const* d_in, const int* in_sizes, int n_in,
                              void* d_out, int out_size, void* d_ws, size_t ws_size,
                              hipStream_t stream) {
    const float* nodes_in = (const float*)d_in[0];   // (B,N,H) f32
    const float* adj      = (const float*)d_in[1];   // (B,E,N) f32, binary
    const float* w1       = (const float*)d_in[2];   // (H+1)
    const float* w2       = (const float*)d_in[3];   // (H+1)

    char* ws = (char*)d_ws;
    size_t off = 0;
    u64* bits     = (u64*)(ws + off); off += (size_t)B_ * NROW * NW * sizeof(u64);   // 2 MB
    u16* Wbuf     = (u16*)(ws + off); off += (size_t)B_ * NROW * NROW * sizeof(u16); // 32 MB
    u16* nodes_bf = (u16*)(ws + off); off += (size_t)B_ * NROW * H_ * sizeof(u16);   // 4 MB
    u16* edge_bf  = (u16*)(ws + off); off += (size_t)B_ * NROW * H_ * sizeof(u16);   // 4 MB
    u16* VTn      = (u16*)(ws + off); off += (size_t)B_ * NEXT * NROW * sizeof(u16); // 4.7 MB
    u16* VTe      = (u16*)(ws + off); off += (size_t)B_ * NEXT * NROW * sizeof(u16); // 4.7 MB
    u16* qs       = (u16*)(ws + off); off += (size_t)B_ * NROW * H_ * sizeof(u16);   // 4 MB

    float* out_nodes = (float*)d_out;                        // (B,N,H)
    float* out_edge  = out_nodes + (size_t)B_ * NROW * H_;   // (B,E,H)

    adj_to_bits<<<dim3(B_ * NROW), dim3(256), 0, stream>>>(adj, bits);
    bits_to_abf<<<dim3(1024), dim3(256), 0, stream>>>(bits, Wbuf);
    to_bf16    <<<dim3(B_ * NROW * H_ / 1024), dim3(256), 0, stream>>>(nodes_in, nodes_bf);
    trans_vtn  <<<dim3(B_ * NEXT), dim3(256), 0, stream>>>(nodes_in, VTn);
    fill_vt_rows<<<dim3(256), dim3(256), 0, stream>>>(VTe);
    // edge_init: edge = (adj @ nodes) / deg   (ones-col of VTn == degree)
    gemm_av<<<dim3(256), dim3(256), 0, stream>>>(Wbuf, VTn, out_edge, edge_bf, VTe, 0);

    const float* ncur = nodes_in;
    for (int s = 0; s < 2; ++s) {
        // alpha: scores vs nodes, aggregate nodes -> new edge
        prep_q    <<<dim3(2048), dim3(256), 0, stream>>>(out_edge, w1, qs);
        gemm_score<<<dim3(B_ * 64), dim3(256), 0, stream>>>(qs, nodes_bf, bits, w1, Wbuf, 0);
        gemm_av   <<<dim3(256), dim3(256), 0, stream>>>(Wbuf, VTn, out_edge, edge_bf, VTe, 1);
        // beta: scores vs edge (mask = adj^T), aggregate edge -> new nodes
        prep_q    <<<dim3(2048), dim3(256), 0, stream>>>(ncur, w2, qs);
        gemm_score<<<dim3(B_ * 64), dim3(256), 0, stream>>>(qs, edge_bf, bits, w2, Wbuf, 1);
        gemm_av   <<<dim3(256), dim3(256), 0, stream>>>(Wbuf, VTe, out_nodes, nodes_bf, VTn,
                                                        s == 0 ? 1 : 0);
        ncur = out_nodes;
    }
}

// Round 14
// 264.792 us; speedup vs baseline: 1.4804x; 1.4804x over previous
//
#include <hip/hip_runtime.h>
#include <cstdint>
#include <cstddef>

#define B_ 16
#define NROW 1024      // E == N == 1024
#define H_ 128
#define NW 16          // u64 words per 1024-bit adjacency row
#define BM 64          // output rows per block

typedef unsigned short u16;
typedef unsigned long long u64;
typedef __attribute__((ext_vector_type(8))) short short8;   // 8 bf16 (4 VGPRs)
typedef __attribute__((ext_vector_type(4))) float f32x4;    // MFMA C/D

__device__ __forceinline__ u16 f2bf(float f) {   // RTNE float->bf16
    unsigned u = __float_as_uint(f);
    return (u16)((u + 0x7fffu + ((u >> 16) & 1u)) >> 16);
}
__device__ __forceinline__ float bf2f(u16 h) {
    return __uint_as_float((unsigned)h << 16);
}

// --- adj (B,E,N) f32 -> bit matrix (B*E rows x 16 u64 words) ---
__global__ void adj_to_bits(const float* __restrict__ adj, u64* __restrict__ bits) {
    int be = blockIdx.x;                      // 16384
    const float* row = adj + (size_t)be * NROW;
    int tid = threadIdx.x, lane = tid & 63, wv = tid >> 6;
    for (int c0 = 0; c0 < NROW; c0 += 256) {
        float v = row[c0 + tid];
        u64 m = __ballot(v != 0.0f);
        if (lane == 0) bits[(size_t)be * NW + (c0 >> 6) + wv] = m;
    }
}

// --- fp32 -> bf16 copy (row-major), 4 elems/thread ---
__global__ void to_bf16(const float* __restrict__ in, u16* __restrict__ out) {
    int i = blockIdx.x * 256 + threadIdx.x;
    float4 v = ((const float4*)in)[i];
    ushort4 r;
    r.x = f2bf(v.x); r.y = f2bf(v.y); r.z = f2bf(v.z); r.w = f2bf(v.w);
    ((ushort4*)out)[i] = r;
}

// --- vt[b][d][n] = bf16(src[b][n][d]), d<128 ---
__global__ void trans_vt(const float* __restrict__ src, u16* __restrict__ vt) {
    int blk = blockIdx.x;                 // B_*128
    int b = blk >> 7, d = blk & 127;
    int t = threadIdx.x;                  // 256 threads x 4 n each
    const float* sp = src + ((size_t)b << 10) * H_ + d;
    ushort4 o;
    o.x = f2bf(sp[(size_t)(t * 4 + 0) * H_]);
    o.y = f2bf(sp[(size_t)(t * 4 + 1) * H_]);
    o.z = f2bf(sp[(size_t)(t * 4 + 2) * H_]);
    o.w = f2bf(sp[(size_t)(t * 4 + 3) * H_]);
    ((ushort4*)(vt + ((size_t)b * H_ + d) * NROW))[t] = o;
}

// --- qs[b][r][k] = bf16(src[b][r][k] * w[k] * log2e) ---
__global__ void prep_q(const float* __restrict__ src, const float* __restrict__ w,
                       u16* __restrict__ qs) {
    int idx = blockIdx.x * 256 + threadIdx.x;   // float4 index
    float4 v = ((const float4*)src)[idx];
    float4 wv = ((const float4*)w)[idx & 31];
    const float L2E = 1.44269504f;
    ushort4 r;
    r.x = f2bf(v.x * wv.x * L2E);
    r.y = f2bf(v.y * wv.y * L2E);
    r.z = f2bf(v.z * wv.z * L2E);
    r.w = f2bf(v.w * wv.w * L2E);
    ((ushort4*)qs)[idx] = r;
}

// --- Fused flash attention phase (never materializes W) ---
// Per block: 64-row M-tile. Loop nt=0..7 over 128-col KV tiles:
//   stage KV[n][k] + VT[d][n] -> S = Qs.KV^T (MFMA) -> mask/leaky/exp2 ->
//   P bf16 to swizzled LDS (+ fp32 row-denoms, bf16-rounded) -> O += P.VT^T.
// MODE=1 (edge_init): P = mask bits as {0,1}; skips Qs/KV/S entirely.
// TM=0: mask=bits[row][col] (alpha). TM=1: mask=bits[col][row] (beta).
// aux=1: also write bf16 row-major copy and VT-layout copy of the output.
// All MFMA fragment patterns identical to the r13-validated kernels.
__global__ void __launch_bounds__(512, 1)
fused_attn(const u16* __restrict__ qs, const u16* __restrict__ kvbf,
           const u16* __restrict__ vt, const u64* __restrict__ bits,
           const float* __restrict__ w,
           float* __restrict__ outf, u16* __restrict__ bfo, u16* __restrict__ vto,
           int TM, int MODE, int aux) {
    __shared__ uint4 Al[BM * 16];     // 16 KB  qs tile [64][128]
    __shared__ uint4 Bk[128 * 16];    // 32 KB  kv tile [n][k]
    __shared__ uint4 Bv[128 * 16];    // 32 KB  V^T tile [d][n]
    __shared__ uint4 Pl[BM * 16];     // 16 KB  P tile [m][n] (reused for O transpose)
    __shared__ float dLds[8 * BM];    // 2 KB   per-wave row denominators

    int blk = blockIdx.x;             // 256
    int xcd = blk & 7;
    int jj = blk >> 3;
    int b = xcd + ((jj & 1) << 3);    // XCD b%8 -> L2 locality
    int mt = jj >> 1;                 // 0..15
    int t = threadIdx.x;
    int lane = t & 63, wv = t >> 6;   // 8 waves
    int r15 = lane & 15, g = lane >> 4;
    int hw = wv >> 2;                 // (col_l>>6) for TM=0 bits word

    if (MODE == 0) {
#pragma unroll
        for (int i = 0; i < 2; ++i) {
            int gi = i * 512 + t;
            int row = gi >> 4, kc = gi & 15;
            Al[row * 16 + (kc ^ (row & 7))] =
                ((const uint4*)qs)[((size_t)(b << 10) + mt * 64 + row) * 16 + kc];
        }
    }
    float wb = (MODE == 0) ? w[H_] * 1.44269504f : 0.f;
    f32x4 acc2[4] = {};
    float dsum[4][4] = {};
    int col_l = wv * 16 + r15;        // S col / O d-col for this lane

    for (int nt = 0; nt < 8; ++nt) {
        if (MODE == 0) {
#pragma unroll
            for (int i = 0; i < 4; ++i) {
                int gi = i * 512 + t;
                int row = gi >> 4, kc = gi & 15;
                Bk[row * 16 + (kc ^ (row & 7))] =
                    ((const uint4*)kvbf)[((size_t)(b << 10) + nt * 128 + row) * 16 + kc];
            }
        }
#pragma unroll
        for (int i = 0; i < 4; ++i) {
            int gi = i * 512 + t;
            int row = gi >> 4, kc = gi & 15;
            Bv[row * 16 + (kc ^ (row & 7))] =
                ((const uint4*)vt)[((size_t)b * H_ + row) * 128 + nt * 16 + kc];
        }
        __syncthreads();

        // --- S = Qs.KV^T for this wave's 16 cols ---
        f32x4 sacc[4] = {};
        if (MODE == 0) {
#pragma unroll
            for (int kk = 0; kk < 4; ++kk) {
                uint4 bv4 = Bk[(wv * 16 + r15) * 16 + ((kk * 4 + g) ^ (r15 & 7))];
                short8 bfr = __builtin_bit_cast(short8, bv4);
#pragma unroll
                for (int mi = 0; mi < 4; ++mi) {
                    uint4 av = Al[(mi * 16 + r15) * 16 + ((kk * 4 + g) ^ (r15 & 7))];
                    sacc[mi] = __builtin_amdgcn_mfma_f32_16x16x32_bf16(
                        __builtin_bit_cast(short8, av), bfr, sacc[mi], 0, 0, 0);
                }
            }
        }

        // --- epilogue: mask + leaky + exp2 -> P (bf16), denom ---
        u64 wrd1 = 0;
        if (TM) wrd1 = bits[((size_t)(b << 10) + nt * 128 + col_l) * NW + mt];
#pragma unroll
        for (int mi = 0; mi < 4; ++mi) {
#pragma unroll
            for (int reg = 0; reg < 4; ++reg) {
                int row_l = mi * 16 + g * 4 + reg;     // C/D: row=(lane>>4)*4+reg
                float ww;
                if (MODE == 1) {
                    u64 wrd = bits[((size_t)(b << 10) + mt * 64 + row_l) * NW + nt * 2 + hw];
                    ww = (float)((wrd >> (col_l & 63)) & 1);
                } else {
                    float p = sacc[mi][reg] + wb;
                    p = p >= 0.f ? p : 0.2f * p;       // LeakyReLU(0.2)
                    u64 wrd = TM ? wrd1
                                 : bits[((size_t)(b << 10) + mt * 64 + row_l) * NW + nt * 2 + hw];
                    int bit = TM ? row_l : (col_l & 63);
                    ww = ((wrd >> bit) & 1) ? exp2f(p) : 0.f;
                }
                u16 h = f2bf(ww);
                dsum[mi][reg] += bf2f(h);              // match numerator rounding
                ((u16*)Pl)[(row_l * 16 + ((col_l >> 3) ^ (row_l & 7))) * 8 + (col_l & 7)] = h;
            }
        }
        __syncthreads();

        // --- O += P.VT^T for this wave's 16 d-cols ---
#pragma unroll
        for (int kk = 0; kk < 4; ++kk) {
            uint4 bv4 = Bv[(wv * 16 + r15) * 16 + ((kk * 4 + g) ^ (r15 & 7))];
            short8 vvv = __builtin_bit_cast(short8, bv4);
#pragma unroll
            for (int mi = 0; mi < 4; ++mi) {
                uint4 pv = Pl[(mi * 16 + r15) * 16 + ((kk * 4 + g) ^ (r15 & 7))];
                acc2[mi] = __builtin_amdgcn_mfma_f32_16x16x32_bf16(
                    __builtin_bit_cast(short8, pv), vvv, acc2[mi], 0, 0, 0);
            }
        }
        __syncthreads();
    }

    // --- denominators: reduce over 16 cols (r15), then across 8 waves ---
#pragma unroll
    for (int mi = 0; mi < 4; ++mi)
#pragma unroll
        for (int reg = 0; reg < 4; ++reg) {
            float v = dsum[mi][reg];
            v += __shfl_xor(v, 1); v += __shfl_xor(v, 2);
            v += __shfl_xor(v, 4); v += __shfl_xor(v, 8);
            dsum[mi][reg] = v;
        }
    if (r15 == 0) {
#pragma unroll
        for (int mi = 0; mi < 4; ++mi)
#pragma unroll
            for (int reg = 0; reg < 4; ++reg)
                dLds[wv * BM + mi * 16 + g * 4 + reg] = dsum[mi][reg];
    }
    __syncthreads();

    // --- normalize + store (fp32 always; bf16 + O into Pl for VT transpose) ---
#pragma unroll
    for (int mi = 0; mi < 4; ++mi) {
#pragma unroll
        for (int reg = 0; reg < 4; ++reg) {
            int row_l = mi * 16 + g * 4 + reg;
            float den = 0.f;
#pragma unroll
            for (int w8 = 0; w8 < 8; ++w8) den += dLds[w8 * BM + row_l];
            float rden = den > 0.f ? 1.0f / den : 0.f;
            float val = acc2[mi][reg] * rden;
            size_t R = (size_t)(b << 10) + mt * 64 + row_l;
            outf[R * H_ + col_l] = val;
            u16 h = f2bf(val);
            if (aux) bfo[R * H_ + col_l] = h;
            ((u16*)Pl)[(row_l * 16 + ((col_l >> 3) ^ (row_l & 7))) * 8 + (col_l & 7)] = h;
        }
    }
    if (aux) {
        __syncthreads();
#pragma unroll
        for (int i = 0; i < 2; ++i) {
            int gi = i * 512 + t;                  // 1024 = 128 d x 8 m-chunks
            int d = gi >> 3, mc = gi & 7;
            u16 tmp[8];
#pragma unroll
            for (int j2 = 0; j2 < 8; ++j2) {
                int m = mc * 8 + j2;
                tmp[j2] = ((u16*)Pl)[(m * 16 + ((d >> 3) ^ (m & 7))) * 8 + (d & 7)];
            }
            uint4 o;
            o.x = (unsigned)tmp[0] | ((unsigned)tmp[1] << 16);
            o.y = (unsigned)tmp[2] | ((unsigned)tmp[3] << 16);
            o.z = (unsigned)tmp[4] | ((unsigned)tmp[5] << 16);
            o.w = (unsigned)tmp[6] | ((unsigned)tmp[7] << 16);
            ((uint4*)vto)[((size_t)b * H_ + d) * 128 + mt * 8 + mc] = o;
        }
    }
}

extern "C" void kernel_launch(void* const* d_in, const int* in_sizes, int n_in,
                              void* d_out, int out_size, void* d_ws, size_t ws_size,
                              hipStream_t stream) {
    const float* nodes_in = (const float*)d_in[0];   // (B,N,H) f32
    const float* adj      = (const float*)d_in[1];   // (B,E,N) f32, binary
    const float* w1       = (const float*)d_in[2];   // (H+1)
    const float* w2       = (const float*)d_in[3];   // (H+1)

    char* ws = (char*)d_ws;
    size_t off = 0;
    u64* bits     = (u64*)(ws + off); off += (size_t)B_ * NROW * NW * sizeof(u64);   // 2 MB
    u16* nodes_bf = (u16*)(ws + off); off += (size_t)B_ * NROW * H_ * sizeof(u16);   // 4 MB
    u16* edge_bf  = (u16*)(ws + off); off += (size_t)B_ * NROW * H_ * sizeof(u16);   // 4 MB
    u16* VTn      = (u16*)(ws + off); off += (size_t)B_ * H_ * NROW * sizeof(u16);   // 4 MB
    u16* VTe      = (u16*)(ws + off); off += (size_t)B_ * H_ * NROW * sizeof(u16);   // 4 MB
    u16* qs       = (u16*)(ws + off); off += (size_t)B_ * NROW * H_ * sizeof(u16);   // 4 MB

    float* out_nodes = (float*)d_out;                        // (B,N,H)
    float* out_edge  = out_nodes + (size_t)B_ * NROW * H_;   // (B,E,H)

    adj_to_bits<<<dim3(B_ * NROW), dim3(256), 0, stream>>>(adj, bits);
    to_bf16    <<<dim3(B_ * NROW * H_ / 1024), dim3(256), 0, stream>>>(nodes_in, nodes_bf);
    trans_vt   <<<dim3(B_ * H_), dim3(256), 0, stream>>>(nodes_in, VTn);
    // edge_init: mean of incident node rows (MODE=1: P = adjacency bits)
    fused_attn <<<dim3(256), dim3(512), 0, stream>>>(
        nodes_bf, nodes_bf, VTn, bits, w1, out_edge, edge_bf, VTe, 0, 1, 0);

    const float* ncur = nodes_in;
    for (int s = 0; s < 2; ++s) {
        // alpha: q=edge, kv=nodes, mask=adj  -> new edge (+bf16 +VTe)
        prep_q    <<<dim3(2048), dim3(256), 0, stream>>>(out_edge, w1, qs);
        fused_attn<<<dim3(256), dim3(512), 0, stream>>>(
            qs, nodes_bf, VTn, bits, w1, out_edge, edge_bf, VTe, 0, 0, 1);
        // beta: q=nodes, kv=edge, mask=adj^T -> new nodes (+bf16 +VTn unless last)
        prep_q    <<<dim3(2048), dim3(256), 0, stream>>>(ncur, w2, qs);
        fused_attn<<<dim3(256), dim3(512), 0, stream>>>(
            qs, edge_bf, VTe, bits, w2, out_nodes, nodes_bf, VTn, 1, 0, s == 0 ? 1 : 0);
        ncur = out_nodes;
    }
}